// Round 1
// baseline (2969.699 us; speedup 1.0000x reference)
//
#include <hip/hip_runtime.h>
#include <cstddef>

#define B_    8
#define H_    32
#define W_    32
#define L_    6
#define R_    384
#define NH_   6
#define DH_   64
#define M_    1365
#define NE_   2304
#define HID_  9216
#define NROW_ 49152   // B*H*W*L
#define BMR_  10920   // B*M

typedef __bf16 bf16x8 __attribute__((ext_vector_type(8)));
typedef float  f32x4  __attribute__((ext_vector_type(4)));

__device__ __forceinline__ unsigned short f2b(float f){
  unsigned u = __float_as_uint(f);
  u = (u + 0x7FFFu + ((u >> 16) & 1u)) >> 16;
  return (unsigned short)u;
}

__device__ __forceinline__ float wsum(float s){
  #pragma unroll
  for (int o = 32; o > 0; o >>= 1) s += __shfl_xor(s, o, 64);
  return s;
}

__device__ __forceinline__ float gelu_tanh(float x){
  float t = tanhf(0.7978845608028654f * (x + 0.044715f * x * x * x));
  return 0.5f * x * (1.0f + t);
}

// ---------------- LN1 + scaled atomic scatter into uniq (B,M,R) ----------------
// 4 rows per block, one wave per row of 384.
__global__ __launch_bounds__(256) void k_ln1_scatter(
    const float* __restrict__ x, const float* __restrict__ lw,
    const float* __restrict__ lb, float* __restrict__ uniq){
  int row  = blockIdx.x * 4 + (threadIdx.x >> 6);
  int lane = threadIdx.x & 63;
  int l  = row % 6;
  int hw = (row / 6) & 1023;
  int b  = row / 6144;
  int h = hw >> 5, w = hw & 31;
  const float* xr = x + (size_t)row * R_;
  float v[6]; float s = 0.f;
  #pragma unroll
  for (int i = 0; i < 6; i++){ v[i] = xr[lane + i*64]; s += v[i]; }
  s = wsum(s);
  float mu = s * (1.f/384.f);
  float qq = 0.f;
  #pragma unroll
  for (int i = 0; i < 6; i++){ float d = v[i]-mu; qq += d*d; }
  qq = wsum(qq);
  float rs = rsqrtf(qq * (1.f/384.f) + 1e-5f);
  int off = (4096 - (4096 >> (2*l))) / 3;            // level offset
  int id  = off + (h >> l) * (32 >> l) + (w >> l);
  float invc = 1.f / (float)(1 << (2*l));            // 1/4^l
  float* ur = uniq + ((size_t)b * M_ + id) * R_;
  #pragma unroll
  for (int i = 0; i < 6; i++){
    int r = lane + i*64;
    float ln = (v[i]-mu)*rs*lw[r] + lb[r];
    atomicAdd(&ur[r], ln * invc);
  }
}

// ---------------- fp32 -> bf16 convert ----------------
__global__ void k_cvt(const float* __restrict__ src, unsigned short* __restrict__ dst, int n){
  int i = blockIdx.x * 256 + threadIdx.x;
  if (i < n) dst[i] = f2b(src[i]);
}

// ---------------- transpose + convert: src K x N fp32 -> dst N x K bf16 ----------------
// all dims multiples of 32 here. block (32,8)
__global__ void k_tcvt(const float* __restrict__ src, unsigned short* __restrict__ dst,
                       int K, int N){
  __shared__ float t[32][33];
  int n0 = blockIdx.x * 32, k0 = blockIdx.y * 32;
  int tx = threadIdx.x, ty = threadIdx.y;
  #pragma unroll
  for (int i = 0; i < 4; i++)
    t[ty + i*8][tx] = src[(size_t)(k0 + ty + i*8) * N + n0 + tx];
  __syncthreads();
  #pragma unroll
  for (int i = 0; i < 4; i++)
    dst[(size_t)(n0 + ty + i*8) * K + k0 + tx] = f2b(t[tx][ty + i*8]);
}

// ---------------- bf16 MFMA GEMM: C(MxN) = A(MxK) @ Bt(NxK)^T + bias ----------------
// EPI 0: fp32 out. EPI 1: gelu -> bf16 out. EPI 2: fp32 out += res (RMW on Cout==res).
template<int EPI>
__global__ __launch_bounds__(256) void k_gemm(
    const unsigned short* __restrict__ A,   // M x K bf16
    const unsigned short* __restrict__ Bt,  // N x K bf16
    const float* __restrict__ bias,         // N
    void* __restrict__ Cout,
    const float* __restrict__ res,
    int Mtot, int N, int K){
  __shared__ unsigned short As[128][72];   // pad 8 shorts: 2-way-free b128 reads
  __shared__ unsigned short Bs[128][72];
  int m0 = blockIdx.x * 128, n0 = blockIdx.y * 128;
  int tid  = threadIdx.x;
  int wv   = tid >> 6, lane = tid & 63;
  int quad = lane >> 4, l16 = lane & 15;
  int wm = (wv >> 1) * 64, wn = (wv & 1) * 64;
  f32x4 acc[4][4];
  #pragma unroll
  for (int a = 0; a < 4; a++)
    #pragma unroll
    for (int bidx = 0; bidx < 4; bidx++) acc[a][bidx] = 0.f;

  for (int k0 = 0; k0 < K; k0 += 64){
    #pragma unroll
    for (int i = 0; i < 4; i++){
      int c = tid + i*256;            // 1024 chunks of 8 shorts
      int rowa = c >> 3, colc = (c & 7) * 8;
      int gm = m0 + rowa;
      uint4 d = make_uint4(0u,0u,0u,0u);
      if (gm < Mtot) d = *(const uint4*)(A + (size_t)gm * K + k0 + colc);
      *(uint4*)(&As[rowa][colc]) = d;
      int gn = n0 + rowa;             // N always multiple of 128
      uint4 e = *(const uint4*)(Bt + (size_t)gn * K + k0 + colc);
      *(uint4*)(&Bs[rowa][colc]) = e;
    }
    __syncthreads();
    #pragma unroll
    for (int ko = 0; ko < 2; ko++){
      bf16x8 af[4], bfr[4];
      #pragma unroll
      for (int t = 0; t < 4; t++){
        af[t]  = *(const bf16x8*)(&As[wm + t*16 + l16][ko*32 + quad*8]);
        bfr[t] = *(const bf16x8*)(&Bs[wn + t*16 + l16][ko*32 + quad*8]);
      }
      #pragma unroll
      for (int mt = 0; mt < 4; mt++)
        #pragma unroll
        for (int nt = 0; nt < 4; nt++)
          acc[mt][nt] = __builtin_amdgcn_mfma_f32_16x16x32_bf16(
              af[mt], bfr[nt], acc[mt][nt], 0, 0, 0);
    }
    __syncthreads();
  }
  // epilogue: D row = quad*4 + i, col = l16 (verified m89/m91 layout)
  #pragma unroll
  for (int mt = 0; mt < 4; mt++){
    #pragma unroll
    for (int i = 0; i < 4; i++){
      int row = m0 + wm + mt*16 + quad*4 + i;
      if (row >= Mtot) continue;
      #pragma unroll
      for (int nt = 0; nt < 4; nt++){
        int col = n0 + wn + nt*16 + l16;
        size_t idx = (size_t)row * N + col;
        float vv = acc[mt][nt][i] + bias[col];
        if (EPI == 1){
          ((unsigned short*)Cout)[idx] = f2b(gelu_tanh(vv));
        } else if (EPI == 2){
          ((float*)Cout)[idx] = vv + res[idx];
        } else {
          ((float*)Cout)[idx] = vv;
        }
      }
    }
  }
}

// ---------------- fp32 flash attention over M=1365 nodes ----------------
// grid (22 qtiles, B*NH). block 256. q,k,v fp32 (B*M,384) head-strided; o bf16.
__global__ __launch_bounds__(256) void k_attn(
    const float* __restrict__ q, const float* __restrict__ k,
    const float* __restrict__ v, unsigned short* __restrict__ o){
  __shared__ float Qs[64][65];
  __shared__ float Ks[64][65];
  __shared__ float Vs[64][65];
  __shared__ float Ss[64][65];
  __shared__ float mrow[64], lrow[64], arow[64];
  int qt = blockIdx.x, bh = blockIdx.y;
  int b = bh / NH_, h = bh % NH_;
  size_t base = (size_t)b * M_ * R_ + (size_t)h * DH_;
  int tid = threadIdx.x;
  int tc = tid & 63, tr4 = tid >> 6;
  #pragma unroll
  for (int i = 0; i < 16; i++){
    int r = tr4 + i*4;
    int gm = qt*64 + r;
    Qs[r][tc] = (gm < M_) ? q[base + (size_t)gm * R_ + tc] : 0.f;
  }
  if (tid < 64){ mrow[tid] = -1e30f; lrow[tid] = 0.f; }
  float O[4][4] = {};
  int br = tid >> 4, bc = tid & 15;
  __syncthreads();
  for (int kt = 0; kt < 22; kt++){
    #pragma unroll
    for (int i = 0; i < 16; i++){
      int r = tr4 + i*4; int gn = kt*64 + r;
      bool okx = gn < M_;
      Ks[r][tc] = okx ? k[base + (size_t)gn * R_ + tc] : 0.f;
      Vs[r][tc] = okx ? v[base + (size_t)gn * R_ + tc] : 0.f;
    }
    __syncthreads();
    float sa[4][4] = {};
    for (int kk = 0; kk < 64; kk++){
      float qv[4], kv[4];
      #pragma unroll
      for (int i2 = 0; i2 < 4; i2++) qv[i2] = Qs[br*4 + i2][kk];
      #pragma unroll
      for (int j = 0; j < 4; j++) kv[j] = Ks[bc*4 + j][kk];
      #pragma unroll
      for (int i2 = 0; i2 < 4; i2++)
        #pragma unroll
        for (int j = 0; j < 4; j++) sa[i2][j] += qv[i2] * kv[j];
    }
    #pragma unroll
    for (int i2 = 0; i2 < 4; i2++)
      #pragma unroll
      for (int j = 0; j < 4; j++){
        int gc = kt*64 + bc*4 + j;
        Ss[br*4 + i2][bc*4 + j] = (gc < M_) ? sa[i2][j] * 0.125f : -1e30f;
      }
    __syncthreads();
    if (tid < 64){
      float mprev = mrow[tid];
      float mx = mprev;
      for (int c = 0; c < 64; c++) mx = fmaxf(mx, Ss[tid][c]);
      float al = __expf(mprev - mx);
      float ssum = 0.f;
      for (int c = 0; c < 64; c++){
        float pp = __expf(Ss[tid][c] - mx); Ss[tid][c] = pp; ssum += pp;
      }
      mrow[tid] = mx; lrow[tid] = lrow[tid]*al + ssum; arow[tid] = al;
    }
    __syncthreads();
    float al[4];
    #pragma unroll
    for (int i2 = 0; i2 < 4; i2++) al[i2] = arow[br*4 + i2];
    #pragma unroll
    for (int i2 = 0; i2 < 4; i2++)
      #pragma unroll
      for (int j = 0; j < 4; j++) O[i2][j] *= al[i2];
    for (int jj = 0; jj < 64; jj++){
      float pv[4], vvv[4];
      #pragma unroll
      for (int i2 = 0; i2 < 4; i2++) pv[i2] = Ss[br*4 + i2][jj];
      #pragma unroll
      for (int j = 0; j < 4; j++) vvv[j] = Vs[jj][bc*4 + j];
      #pragma unroll
      for (int i2 = 0; i2 < 4; i2++)
        #pragma unroll
        for (int j = 0; j < 4; j++) O[i2][j] += pv[i2] * vvv[j];
    }
    __syncthreads();
  }
  #pragma unroll
  for (int i2 = 0; i2 < 4; i2++){
    int r = br*4 + i2; int gm = qt*64 + r;
    if (gm < M_){
      float il = 1.f / lrow[r];
      #pragma unroll
      for (int j = 0; j < 4; j++)
        o[base + (size_t)gm * R_ + bc*4 + j] = f2b(O[i2][j] * il);
    }
  }
}

// ---------------- scatter attn_out + residual -> d_out; LN2 -> flat bf16 ----------------
__global__ __launch_bounds__(256) void k_scatter_ln2(
    const float* __restrict__ x, const float* __restrict__ attn,
    const float* __restrict__ lw, const float* __restrict__ lb,
    float* __restrict__ xres, unsigned short* __restrict__ flatb){
  int row  = blockIdx.x * 4 + (threadIdx.x >> 6);
  int lane = threadIdx.x & 63;
  int l  = row % 6;
  int hw = (row / 6) & 1023;
  int b  = row / 6144;
  int h = hw >> 5, w = hw & 31;
  int off = (4096 - (4096 >> (2*l))) / 3;
  int id  = off + (h >> l) * (32 >> l) + (w >> l);
  const float* ar = attn + ((size_t)b * M_ + id) * R_;
  const float* xr = x + (size_t)row * R_;
  float* orow = xres + (size_t)row * R_;
  float vv[6]; float s = 0.f;
  #pragma unroll
  for (int i = 0; i < 6; i++){
    int r = lane + i*64;
    float t = xr[r] + ar[r];
    vv[i] = t; s += t; orow[r] = t;
  }
  s = wsum(s);
  float mu = s * (1.f/384.f);
  float qq = 0.f;
  #pragma unroll
  for (int i = 0; i < 6; i++){ float d = vv[i]-mu; qq += d*d; }
  qq = wsum(qq);
  float rs = rsqrtf(qq * (1.f/384.f) + 1e-5f);
  unsigned short* fr = flatb + (size_t)row * R_;
  #pragma unroll
  for (int i = 0; i < 6; i++){
    int r = lane + i*64;
    fr[r] = f2b((vv[i]-mu)*rs*lw[r] + lb[r]);
  }
}

extern "C" void kernel_launch(void* const* d_in, const int* in_sizes, int n_in,
                              void* d_out, int out_size, void* d_ws, size_t ws_size,
                              hipStream_t stream){
  const float* x    = (const float*)d_in[0];
  const float* ln1w = (const float*)d_in[1];
  const float* ln1b = (const float*)d_in[2];
  const float* ln2w = (const float*)d_in[3];
  const float* ln2b = (const float*)d_in[4];
  const float* wq   = (const float*)d_in[5];
  const float* bq   = (const float*)d_in[6];
  const float* wk   = (const float*)d_in[7];
  const float* bk   = (const float*)d_in[8];
  const float* wvv  = (const float*)d_in[9];
  const float* bv   = (const float*)d_in[10];
  const float* wo   = (const float*)d_in[11];
  const float* bo   = (const float*)d_in[12];
  const float* w1   = (const float*)d_in[13];
  const float* b1   = (const float*)d_in[14];
  const float* w2   = (const float*)d_in[15];
  const float* b2   = (const float*)d_in[16];
  float* out = (float*)d_out;

  // ---- workspace layout ----
  // Region A (first 151.0 MB): q,k,v,o,attn_out live until scatter; then the
  // whole region is reused as h1b (MLP hidden, bf16) -- lifetimes are disjoint.
  char* ws = (char*)d_ws;
  unsigned short* h1b = (unsigned short*)ws;                    // 8192*9216 bf16
  float* qf = (float*)ws;
  float* kf = qf + (size_t)BMR_ * R_;
  float* vf = kf + (size_t)BMR_ * R_;
  unsigned short* ob = (unsigned short*)(vf + (size_t)BMR_ * R_);
  float* attn_o = (float*)(ob + (size_t)BMR_ * R_);             // ends at 75.5MB < 151MB
  size_t regA = ((size_t)8192 * HID_ * 2 + 255) & ~(size_t)255;
  char* p = ws + regA;
  float* uniqf = (float*)p;                 p += (size_t)BMR_ * R_ * 4;
  unsigned short* uniqb = (unsigned short*)p; p += (size_t)BMR_ * R_ * 2;
  unsigned short* wqt = (unsigned short*)p;   p += (size_t)R_ * R_ * 2;
  unsigned short* wkt = (unsigned short*)p;   p += (size_t)R_ * R_ * 2;
  unsigned short* wvt = (unsigned short*)p;   p += (size_t)R_ * R_ * 2;
  unsigned short* wot = (unsigned short*)p;   p += (size_t)R_ * R_ * 2;
  unsigned short* w1t = (unsigned short*)p;   p += (size_t)NE_ * HID_ * 2;
  unsigned short* w2t = (unsigned short*)p;   p += (size_t)NE_ * HID_ * 2;
  unsigned short* flatb = (unsigned short*)p; p += (size_t)NROW_ * R_ * 2;
  // total ~300 MB

  hipMemsetAsync(uniqf, 0, (size_t)BMR_ * R_ * 4, stream);
  k_ln1_scatter<<<NROW_/4, 256, 0, stream>>>(x, ln1w, ln1b, uniqf);
  k_cvt<<<(BMR_*R_ + 255)/256, 256, 0, stream>>>(uniqf, uniqb, BMR_*R_);

  dim3 tb(32, 8);
  k_tcvt<<<dim3(R_/32, R_/32), tb, 0, stream>>>(wq, wqt, R_, R_);
  k_tcvt<<<dim3(R_/32, R_/32), tb, 0, stream>>>(wk, wkt, R_, R_);
  k_tcvt<<<dim3(R_/32, R_/32), tb, 0, stream>>>(wvv, wvt, R_, R_);
  k_tcvt<<<dim3(R_/32, R_/32), tb, 0, stream>>>(wo, wot, R_, R_);
  k_tcvt<<<dim3(HID_/32, NE_/32), tb, 0, stream>>>(w1, w1t, NE_, HID_);
  k_tcvt<<<dim3(NE_/32, HID_/32), tb, 0, stream>>>(w2, w2t, HID_, NE_);

  k_gemm<0><<<dim3(86, 3), 256, 0, stream>>>(uniqb, wqt, bq, qf, nullptr, BMR_, R_, R_);
  k_gemm<0><<<dim3(86, 3), 256, 0, stream>>>(uniqb, wkt, bk, kf, nullptr, BMR_, R_, R_);
  k_gemm<0><<<dim3(86, 3), 256, 0, stream>>>(uniqb, wvt, bv, vf, nullptr, BMR_, R_, R_);

  k_attn<<<dim3(22, 48), 256, 0, stream>>>(qf, kf, vf, ob);

  k_gemm<0><<<dim3(86, 3), 256, 0, stream>>>(ob, wot, bo, attn_o, nullptr, BMR_, R_, R_);

  k_scatter_ln2<<<NROW_/4, 256, 0, stream>>>(x, attn_o, ln2w, ln2b, out, flatb);

  k_gemm<1><<<dim3(64, 72), 256, 0, stream>>>(flatb, w1t, b1, h1b, nullptr, 8192, HID_, NE_);
  k_gemm<2><<<dim3(64, 18), 256, 0, stream>>>(h1b, w2t, b2, out, out, 8192, NE_, HID_);
}

// Round 2
// 2132.427 us; speedup vs baseline: 1.3926x; 1.3926x over previous
//
#include <hip/hip_runtime.h>
#include <cstddef>

#define B_    8
#define H_    32
#define W_    32
#define L_    6
#define R_    384
#define NH_   6
#define DH_   64
#define M_    1365
#define MPAD_ 1408
#define NE_   2304
#define HID_  9216
#define NROW_ 49152   // B*H*W*L
#define BMR_  10920   // B*M

typedef __bf16 bf16x8 __attribute__((ext_vector_type(8)));
typedef float  f32x4  __attribute__((ext_vector_type(4)));

__device__ __forceinline__ unsigned short f2b(float f){
  unsigned u = __float_as_uint(f);
  u = (u + 0x7FFFu + ((u >> 16) & 1u)) >> 16;
  return (unsigned short)u;
}

__device__ __forceinline__ float wsum(float s){
  #pragma unroll
  for (int o = 32; o > 0; o >>= 1) s += __shfl_xor(s, o, 64);
  return s;
}

__device__ __forceinline__ float rmax16(float v){
  v = fmaxf(v, __shfl_xor(v, 1, 64));
  v = fmaxf(v, __shfl_xor(v, 2, 64));
  v = fmaxf(v, __shfl_xor(v, 4, 64));
  v = fmaxf(v, __shfl_xor(v, 8, 64));
  return v;
}
__device__ __forceinline__ float rsum16(float v){
  v += __shfl_xor(v, 1, 64);
  v += __shfl_xor(v, 2, 64);
  v += __shfl_xor(v, 4, 64);
  v += __shfl_xor(v, 8, 64);
  return v;
}

__device__ __forceinline__ float gelu_tanh(float x){
  float t = tanhf(0.7978845608028654f * (x + 0.044715f * x * x * x));
  return 0.5f * x * (1.0f + t);
}

// ---------------- LN1 + scaled atomic scatter into uniq (B,M,R) ----------------
__global__ __launch_bounds__(256) void k_ln1_scatter(
    const float* __restrict__ x, const float* __restrict__ lw,
    const float* __restrict__ lb, float* __restrict__ uniq){
  int row  = blockIdx.x * 4 + (threadIdx.x >> 6);
  int lane = threadIdx.x & 63;
  int l  = row % 6;
  int hw = (row / 6) & 1023;
  int b  = row / 6144;
  int h = hw >> 5, w = hw & 31;
  const float* xr = x + (size_t)row * R_;
  float v[6]; float s = 0.f;
  #pragma unroll
  for (int i = 0; i < 6; i++){ v[i] = xr[lane + i*64]; s += v[i]; }
  s = wsum(s);
  float mu = s * (1.f/384.f);
  float qq = 0.f;
  #pragma unroll
  for (int i = 0; i < 6; i++){ float d = v[i]-mu; qq += d*d; }
  qq = wsum(qq);
  float rs = rsqrtf(qq * (1.f/384.f) + 1e-5f);
  int off = (4096 - (4096 >> (2*l))) / 3;
  int id  = off + (h >> l) * (32 >> l) + (w >> l);
  float invc = 1.f / (float)(1 << (2*l));
  float* ur = uniq + ((size_t)b * M_ + id) * R_;
  #pragma unroll
  for (int i = 0; i < 6; i++){
    int r = lane + i*64;
    float ln = (v[i]-mu)*rs*lw[r] + lb[r];
    atomicAdd(&ur[r], ln * invc);
  }
}

// ---------------- fp32 -> bf16 convert ----------------
__global__ void k_cvt(const float* __restrict__ src, unsigned short* __restrict__ dst, int n){
  int i = blockIdx.x * 256 + threadIdx.x;
  if (i < n) dst[i] = f2b(src[i]);
}

// ---------------- transpose + convert: src K x N fp32 -> dst N x K bf16 ----------------
__global__ void k_tcvt(const float* __restrict__ src, unsigned short* __restrict__ dst,
                       int K, int N){
  __shared__ float t[32][33];
  int n0 = blockIdx.x * 32, k0 = blockIdx.y * 32;
  int tx = threadIdx.x, ty = threadIdx.y;
  #pragma unroll
  for (int i = 0; i < 4; i++)
    t[ty + i*8][tx] = src[(size_t)(k0 + ty + i*8) * N + n0 + tx];
  __syncthreads();
  #pragma unroll
  for (int i = 0; i < 4; i++)
    dst[(size_t)(n0 + ty + i*8) * K + k0 + tx] = f2b(t[tx][ty + i*8]);
}

// ---------------- bf16 MFMA GEMM: C(MxN) = A(MxK) @ Bt(NxK)^T + bias ----------------
// EPI 0: fp32 out. EPI 1: gelu -> bf16. EPI 2: fp32 out += res (RMW).
// EPI 3: bf16 transposed V store into (B,NH,DH,MPAD). EPI 4: bf16 row-major.
template<int EPI>
__global__ __launch_bounds__(256) void k_gemm(
    const unsigned short* __restrict__ A,   // M x K bf16
    const unsigned short* __restrict__ Bt,  // N x K bf16
    const float* __restrict__ bias,         // N
    void* __restrict__ Cout,
    const float* __restrict__ res,
    int Mtot, int N, int K){
  __shared__ unsigned short As[128][72];
  __shared__ unsigned short Bs[128][72];
  int m0 = blockIdx.x * 128, n0 = blockIdx.y * 128;
  int tid  = threadIdx.x;
  int wv   = tid >> 6, lane = tid & 63;
  int quad = lane >> 4, l16 = lane & 15;
  int wm = (wv >> 1) * 64, wn = (wv & 1) * 64;
  f32x4 acc[4][4];
  #pragma unroll
  for (int a = 0; a < 4; a++)
    #pragma unroll
    for (int bidx = 0; bidx < 4; bidx++) acc[a][bidx] = 0.f;

  for (int k0 = 0; k0 < K; k0 += 64){
    #pragma unroll
    for (int i = 0; i < 4; i++){
      int c = tid + i*256;
      int rowa = c >> 3, colc = (c & 7) * 8;
      int gm = m0 + rowa;
      uint4 d = make_uint4(0u,0u,0u,0u);
      if (gm < Mtot) d = *(const uint4*)(A + (size_t)gm * K + k0 + colc);
      *(uint4*)(&As[rowa][colc]) = d;
      int gn = n0 + rowa;
      uint4 e = *(const uint4*)(Bt + (size_t)gn * K + k0 + colc);
      *(uint4*)(&Bs[rowa][colc]) = e;
    }
    __syncthreads();
    #pragma unroll
    for (int ko = 0; ko < 2; ko++){
      bf16x8 af[4], bfr[4];
      #pragma unroll
      for (int t = 0; t < 4; t++){
        af[t]  = *(const bf16x8*)(&As[wm + t*16 + l16][ko*32 + quad*8]);
        bfr[t] = *(const bf16x8*)(&Bs[wn + t*16 + l16][ko*32 + quad*8]);
      }
      #pragma unroll
      for (int mt = 0; mt < 4; mt++)
        #pragma unroll
        for (int nt = 0; nt < 4; nt++)
          acc[mt][nt] = __builtin_amdgcn_mfma_f32_16x16x32_bf16(
              af[mt], bfr[nt], acc[mt][nt], 0, 0, 0);
    }
    __syncthreads();
  }
  #pragma unroll
  for (int mt = 0; mt < 4; mt++){
    #pragma unroll
    for (int i = 0; i < 4; i++){
      int row = m0 + wm + mt*16 + quad*4 + i;
      if (row >= Mtot) continue;
      #pragma unroll
      for (int nt = 0; nt < 4; nt++){
        int col = n0 + wn + nt*16 + l16;
        size_t idx = (size_t)row * N + col;
        float vv = acc[mt][nt][i] + bias[col];
        if (EPI == 1){
          ((unsigned short*)Cout)[idx] = f2b(gelu_tanh(vv));
        } else if (EPI == 2){
          ((float*)Cout)[idx] = vv + res[idx];
        } else if (EPI == 3){
          int bb = row / M_;
          int mm = row - bb * M_;
          int hh = col >> 6, dd = col & 63;
          ((unsigned short*)Cout)[(((size_t)(bb*NH_ + hh))*DH_ + dd)*MPAD_ + mm] = f2b(vv);
        } else if (EPI == 4){
          ((unsigned short*)Cout)[idx] = f2b(vv);
        } else {
          ((float*)Cout)[idx] = vv;
        }
      }
    }
  }
}

// ---------------- bf16 MFMA flash attention over M=1365 nodes ----------------
// grid (22, B*NH). block 256 (4 waves, 16 q-rows each).
// qb,kb: bf16 (BMR,384) row-major; vtb: bf16 (B,NH,64,MPAD); ob: bf16 (BMR,384).
__global__ __launch_bounds__(256) void k_attn(
    const unsigned short* __restrict__ qb, const unsigned short* __restrict__ kb,
    const unsigned short* __restrict__ vtb, unsigned short* __restrict__ ob){
  __shared__ unsigned short Ks[64][64];
  __shared__ unsigned short Vt[64][64];
  __shared__ unsigned short Ps[4][16][64];
  int qt = blockIdx.x, bh = blockIdx.y;
  int b = bh / NH_, h = bh % NH_;
  int tid = threadIdx.x, wv = tid >> 6, lane = tid & 63;
  int quad = lane >> 4, l16 = lane & 15;

  // Q A-frags (row m = l16 within wave's 16 rows; k = quad*8..+7 per ko)
  int qm = qt*64 + wv*16 + l16;
  const unsigned short* qrow = qb + (size_t)(b*M_ + qm)*R_ + h*DH_;
  bf16x8 aq0 = *(const bf16x8*)(qrow + quad*8);
  bf16x8 aq1 = *(const bf16x8*)(qrow + 32 + quad*8);

  f32x4 oacc[4];
  #pragma unroll
  for (int db = 0; db < 4; db++) oacc[db] = 0.f;
  float mi[4], li[4];
  #pragma unroll
  for (int i = 0; i < 4; i++){ mi[i] = -1e30f; li[i] = 0.f; }

  for (int kt = 0; kt < 22; kt++){
    // stage K tile (row n=kv, col d) and Vt tile (row d, col kv)
    #pragma unroll
    for (int i = 0; i < 2; i++){
      int c = tid + i*256;
      int rowa = c >> 3, colc = (c & 7) * 8;
      *(uint4*)(&Ks[rowa][colc]) =
        *(const uint4*)(kb + (size_t)(b*M_ + kt*64 + rowa)*R_ + h*DH_ + colc);
      *(uint4*)(&Vt[rowa][colc]) =
        *(const uint4*)(vtb + ((size_t)bh*DH_ + rowa)*MPAD_ + kt*64 + colc);
    }
    __syncthreads();

    // S = Q(16xK=64) @ K^T -> 4 n-blocks, C layout
    f32x4 s[4];
    #pragma unroll
    for (int nb = 0; nb < 4; nb++){
      s[nb] = 0.f;
      bf16x8 bk0 = *(const bf16x8*)(&Ks[nb*16 + l16][quad*8]);
      bf16x8 bk1 = *(const bf16x8*)(&Ks[nb*16 + l16][32 + quad*8]);
      s[nb] = __builtin_amdgcn_mfma_f32_16x16x32_bf16(aq0, bk0, s[nb], 0, 0, 0);
      s[nb] = __builtin_amdgcn_mfma_f32_16x16x32_bf16(aq1, bk1, s[nb], 0, 0, 0);
    }

    // online softmax per C-layout row r = quad*4 + i
    #pragma unroll
    for (int i = 0; i < 4; i++){
      float val[4];
      float mx = -1e30f;
      #pragma unroll
      for (int nb = 0; nb < 4; nb++){
        int gc = kt*64 + nb*16 + l16;
        val[nb] = (gc < M_) ? s[nb][i] * 0.125f : -1e30f;
        mx = fmaxf(mx, val[nb]);
      }
      mx = rmax16(mx);
      float mnew = fmaxf(mi[i], mx);
      float alpha = __expf(mi[i] - mnew);
      float rs = 0.f;
      #pragma unroll
      for (int nb = 0; nb < 4; nb++){
        float p = __expf(val[nb] - mnew);
        rs += p;
        Ps[wv][quad*4 + i][nb*16 + l16] = f2b(p);
      }
      rs = rsum16(rs);
      li[i] = li[i]*alpha + rs;
      mi[i] = mnew;
      #pragma unroll
      for (int db = 0; db < 4; db++) oacc[db][i] *= alpha;
    }

    // O += P(16x64) @ V(64x64)  (same-wave DS ordering makes Ps RAW safe)
    #pragma unroll
    for (int ko = 0; ko < 2; ko++){
      bf16x8 ap = *(const bf16x8*)(&Ps[wv][l16][ko*32 + quad*8]);
      #pragma unroll
      for (int db = 0; db < 4; db++){
        bf16x8 bv = *(const bf16x8*)(&Vt[db*16 + l16][ko*32 + quad*8]);
        oacc[db] = __builtin_amdgcn_mfma_f32_16x16x32_bf16(ap, bv, oacc[db], 0, 0, 0);
      }
    }
    __syncthreads();
  }

  // epilogue
  #pragma unroll
  for (int i = 0; i < 4; i++){
    int gm = qt*64 + wv*16 + quad*4 + i;
    if (gm < M_){
      float il = 1.f / li[i];
      #pragma unroll
      for (int db = 0; db < 4; db++)
        ob[(size_t)(b*M_ + gm)*R_ + h*DH_ + db*16 + l16] = f2b(oacc[db][i] * il);
    }
  }
}

// ---------------- scatter attn_out + residual -> d_out; LN2 -> flat bf16 ----------------
__global__ __launch_bounds__(256) void k_scatter_ln2(
    const float* __restrict__ x, const float* __restrict__ attn,
    const float* __restrict__ lw, const float* __restrict__ lb,
    float* __restrict__ xres, unsigned short* __restrict__ flatb){
  int row  = blockIdx.x * 4 + (threadIdx.x >> 6);
  int lane = threadIdx.x & 63;
  int l  = row % 6;
  int hw = (row / 6) & 1023;
  int b  = row / 6144;
  int h = hw >> 5, w = hw & 31;
  int off = (4096 - (4096 >> (2*l))) / 3;
  int id  = off + (h >> l) * (32 >> l) + (w >> l);
  const float* ar = attn + ((size_t)b * M_ + id) * R_;
  const float* xr = x + (size_t)row * R_;
  float* orow = xres + (size_t)row * R_;
  float vv[6]; float s = 0.f;
  #pragma unroll
  for (int i = 0; i < 6; i++){
    int r = lane + i*64;
    float t = xr[r] + ar[r];
    vv[i] = t; s += t; orow[r] = t;
  }
  s = wsum(s);
  float mu = s * (1.f/384.f);
  float qq = 0.f;
  #pragma unroll
  for (int i = 0; i < 6; i++){ float d = vv[i]-mu; qq += d*d; }
  qq = wsum(qq);
  float rs = rsqrtf(qq * (1.f/384.f) + 1e-5f);
  unsigned short* fr = flatb + (size_t)row * R_;
  #pragma unroll
  for (int i = 0; i < 6; i++){
    int r = lane + i*64;
    fr[r] = f2b((vv[i]-mu)*rs*lw[r] + lb[r]);
  }
}

extern "C" void kernel_launch(void* const* d_in, const int* in_sizes, int n_in,
                              void* d_out, int out_size, void* d_ws, size_t ws_size,
                              hipStream_t stream){
  const float* x    = (const float*)d_in[0];
  const float* ln1w = (const float*)d_in[1];
  const float* ln1b = (const float*)d_in[2];
  const float* ln2w = (const float*)d_in[3];
  const float* ln2b = (const float*)d_in[4];
  const float* wq   = (const float*)d_in[5];
  const float* bq   = (const float*)d_in[6];
  const float* wk   = (const float*)d_in[7];
  const float* bk   = (const float*)d_in[8];
  const float* wvv  = (const float*)d_in[9];
  const float* bv   = (const float*)d_in[10];
  const float* wo   = (const float*)d_in[11];
  const float* bo   = (const float*)d_in[12];
  const float* w1   = (const float*)d_in[13];
  const float* b1   = (const float*)d_in[14];
  const float* w2   = (const float*)d_in[15];
  const float* b2   = (const float*)d_in[16];
  float* out = (float*)d_out;

  // ---- workspace layout ----
  // Region A (first 151 MB, reused as h1b during MLP): qb,kb,vtb,ob,attn_o.
  char* ws = (char*)d_ws;
  unsigned short* h1b = (unsigned short*)ws;                     // 8192*9216 bf16
  unsigned short* qb  = (unsigned short*)ws;
  unsigned short* kb  = qb + (size_t)BMR_ * R_;
  unsigned short* vtb = kb + (size_t)BMR_ * R_;
  unsigned short* ob  = vtb + (size_t)B_ * NH_ * DH_ * MPAD_;
  float* attn_o = (float*)(ob + (size_t)BMR_ * R_);
  size_t regA = ((size_t)8192 * HID_ * 2 + 255) & ~(size_t)255;
  char* p = ws + regA;
  float* uniqf = (float*)p;                   p += (size_t)BMR_ * R_ * 4;
  unsigned short* uniqb = (unsigned short*)p; p += (size_t)BMR_ * R_ * 2;
  unsigned short* wqt = (unsigned short*)p;   p += (size_t)R_ * R_ * 2;
  unsigned short* wkt = (unsigned short*)p;   p += (size_t)R_ * R_ * 2;
  unsigned short* wvt = (unsigned short*)p;   p += (size_t)R_ * R_ * 2;
  unsigned short* wot = (unsigned short*)p;   p += (size_t)R_ * R_ * 2;
  unsigned short* w1t = (unsigned short*)p;   p += (size_t)NE_ * HID_ * 2;
  unsigned short* w2t = (unsigned short*)p;   p += (size_t)NE_ * HID_ * 2;
  unsigned short* flatb = (unsigned short*)p; p += (size_t)NROW_ * R_ * 2;

  hipMemsetAsync(uniqf, 0, (size_t)BMR_ * R_ * 4, stream);
  hipMemsetAsync(vtb, 0, (size_t)B_ * NH_ * DH_ * MPAD_ * 2, stream);
  k_ln1_scatter<<<NROW_/4, 256, 0, stream>>>(x, ln1w, ln1b, uniqf);
  k_cvt<<<(BMR_*R_ + 255)/256, 256, 0, stream>>>(uniqf, uniqb, BMR_*R_);

  dim3 tb(32, 8);
  k_tcvt<<<dim3(R_/32, R_/32), tb, 0, stream>>>(wq, wqt, R_, R_);
  k_tcvt<<<dim3(R_/32, R_/32), tb, 0, stream>>>(wk, wkt, R_, R_);
  k_tcvt<<<dim3(R_/32, R_/32), tb, 0, stream>>>(wvv, wvt, R_, R_);
  k_tcvt<<<dim3(R_/32, R_/32), tb, 0, stream>>>(wo, wot, R_, R_);
  k_tcvt<<<dim3(HID_/32, NE_/32), tb, 0, stream>>>(w1, w1t, NE_, HID_);
  k_tcvt<<<dim3(NE_/32, HID_/32), tb, 0, stream>>>(w2, w2t, HID_, NE_);

  k_gemm<4><<<dim3(86, 3), 256, 0, stream>>>(uniqb, wqt, bq, qb, nullptr, BMR_, R_, R_);
  k_gemm<4><<<dim3(86, 3), 256, 0, stream>>>(uniqb, wkt, bk, kb, nullptr, BMR_, R_, R_);
  k_gemm<3><<<dim3(86, 3), 256, 0, stream>>>(uniqb, wvt, bv, vtb, nullptr, BMR_, R_, R_);

  k_attn<<<dim3(22, 48), 256, 0, stream>>>(qb, kb, vtb, ob);

  k_gemm<0><<<dim3(86, 3), 256, 0, stream>>>(ob, wot, bo, attn_o, nullptr, BMR_, R_, R_);

  k_scatter_ln2<<<NROW_/4, 256, 0, stream>>>(x, attn_o, ln2w, ln2b, out, flatb);

  k_gemm<1><<<dim3(64, 72), 256, 0, stream>>>(flatb, w1t, b1, h1b, nullptr, 8192, HID_, NE_);
  k_gemm<2><<<dim3(64, 18), 256, 0, stream>>>(h1b, w2t, b2, out, out, 8192, NE_, HID_);
}

// Round 3
// 2009.890 us; speedup vs baseline: 1.4775x; 1.0610x over previous
//
#include <hip/hip_runtime.h>
#include <cstddef>

#define B_    8
#define H_    32
#define W_    32
#define L_    6
#define R_    384
#define NH_   6
#define DH_   64
#define M_    1365
#define MPAD_ 1408
#define NE_   2304
#define HID_  9216
#define NROW_ 49152   // B*H*W*L
#define BMR_  10920   // B*M

typedef __bf16 bf16x8 __attribute__((ext_vector_type(8)));
typedef float  f32x4  __attribute__((ext_vector_type(4)));

__device__ __forceinline__ unsigned short f2b(float f){
  unsigned u = __float_as_uint(f);
  u = (u + 0x7FFFu + ((u >> 16) & 1u)) >> 16;
  return (unsigned short)u;
}

__device__ __forceinline__ void gload16(const unsigned short* g, unsigned short* l){
  __builtin_amdgcn_global_load_lds(
      (const __attribute__((address_space(1))) unsigned int*)g,
      (__attribute__((address_space(3))) unsigned int*)l,
      16, 0, 0);
}

__device__ __forceinline__ float wsum(float s){
  #pragma unroll
  for (int o = 32; o > 0; o >>= 1) s += __shfl_xor(s, o, 64);
  return s;
}

__device__ __forceinline__ float rmax16(float v){
  v = fmaxf(v, __shfl_xor(v, 1, 64));
  v = fmaxf(v, __shfl_xor(v, 2, 64));
  v = fmaxf(v, __shfl_xor(v, 4, 64));
  v = fmaxf(v, __shfl_xor(v, 8, 64));
  return v;
}
__device__ __forceinline__ float rsum16(float v){
  v += __shfl_xor(v, 1, 64);
  v += __shfl_xor(v, 2, 64);
  v += __shfl_xor(v, 4, 64);
  v += __shfl_xor(v, 8, 64);
  return v;
}

__device__ __forceinline__ float gelu_tanh(float x){
  float t = tanhf(0.7978845608028654f * (x + 0.044715f * x * x * x));
  return 0.5f * x * (1.0f + t);
}

// ---------------- LN1 + scaled atomic scatter into uniq (B,M,R) ----------------
__global__ __launch_bounds__(256) void k_ln1_scatter(
    const float* __restrict__ x, const float* __restrict__ lw,
    const float* __restrict__ lb, float* __restrict__ uniq){
  int row  = blockIdx.x * 4 + (threadIdx.x >> 6);
  int lane = threadIdx.x & 63;
  int l  = row % 6;
  int hw = (row / 6) & 1023;
  int b  = row / 6144;
  int h = hw >> 5, w = hw & 31;
  const float* xr = x + (size_t)row * R_;
  float v[6]; float s = 0.f;
  #pragma unroll
  for (int i = 0; i < 6; i++){ v[i] = xr[lane + i*64]; s += v[i]; }
  s = wsum(s);
  float mu = s * (1.f/384.f);
  float qq = 0.f;
  #pragma unroll
  for (int i = 0; i < 6; i++){ float d = v[i]-mu; qq += d*d; }
  qq = wsum(qq);
  float rs = rsqrtf(qq * (1.f/384.f) + 1e-5f);
  int off = (4096 - (4096 >> (2*l))) / 3;
  int id  = off + (h >> l) * (32 >> l) + (w >> l);
  float invc = 1.f / (float)(1 << (2*l));
  float* ur = uniq + ((size_t)b * M_ + id) * R_;
  #pragma unroll
  for (int i = 0; i < 6; i++){
    int r = lane + i*64;
    float ln = (v[i]-mu)*rs*lw[r] + lb[r];
    atomicAdd(&ur[r], ln * invc);
  }
}

// ---------------- fp32 -> bf16 convert ----------------
__global__ void k_cvt(const float* __restrict__ src, unsigned short* __restrict__ dst, int n){
  int i = blockIdx.x * 256 + threadIdx.x;
  if (i < n) dst[i] = f2b(src[i]);
}

// ---------------- transpose + convert: src K x N fp32 -> dst N x K bf16 ----------------
__global__ void k_tcvt(const float* __restrict__ src, unsigned short* __restrict__ dst,
                       int K, int N){
  __shared__ float t[32][33];
  int n0 = blockIdx.x * 32, k0 = blockIdx.y * 32;
  int tx = threadIdx.x, ty = threadIdx.y;
  #pragma unroll
  for (int i = 0; i < 4; i++)
    t[ty + i*8][tx] = src[(size_t)(k0 + ty + i*8) * N + n0 + tx];
  __syncthreads();
  #pragma unroll
  for (int i = 0; i < 4; i++)
    dst[(size_t)(n0 + ty + i*8) * K + k0 + tx] = f2b(t[tx][ty + i*8]);
}

// ---------------- bf16 MFMA GEMM: C(MxN) = A(MxK) @ Bt(NxK)^T + bias ----------------
// Staging via global_load_lds width=16 (m97 structure): unpadded LDS [128][64].
// EPI 0: fp32 out. EPI 1: gelu -> bf16. EPI 2: fp32 out += res (RMW).
// EPI 5: merged QKV routing (Cout=qb row-major, aux1=kb row-major, aux2=vt transposed).
template<int EPI>
__global__ __launch_bounds__(256) void k_gemm(
    const unsigned short* __restrict__ A,   // M x K bf16
    const unsigned short* __restrict__ Bt,  // N x K bf16
    const float* __restrict__ bias,         // N
    void* __restrict__ Cout,
    const float* __restrict__ res,
    void* __restrict__ aux1, void* __restrict__ aux2,
    int Mtot, int N, int K){
  __shared__ unsigned short As[128*64];
  __shared__ unsigned short Bs[128*64];
  int m0 = blockIdx.x * 128, n0 = blockIdx.y * 128;
  int tid  = threadIdx.x;
  int wv   = tid >> 6, lane = tid & 63;
  int quad = lane >> 4, l16 = lane & 15;
  int wm = (wv >> 1) * 64, wn = (wv & 1) * 64;
  int lr = lane >> 3;          // row within 8-row chunk
  int lc = (lane & 7) * 8;     // short col within 64-col row
  f32x4 acc[4][4];
  #pragma unroll
  for (int a = 0; a < 4; a++)
    #pragma unroll
    for (int bidx = 0; bidx < 4; bidx++) acc[a][bidx] = 0.f;

  for (int k0 = 0; k0 < K; k0 += 64){
    #pragma unroll
    for (int j = 0; j < 4; j++){
      int c = wv*4 + j;            // chunk 0..15, 8 rows each
      int rowa = c*8 + lr;
      int gm = m0 + rowa; if (gm >= Mtot) gm = Mtot - 1;
      gload16(A + (size_t)gm * K + k0 + lc, &As[c*512]);
      int gn = n0 + rowa;          // N multiple of 128
      gload16(Bt + (size_t)gn * K + k0 + lc, &Bs[c*512]);
    }
    asm volatile("s_waitcnt vmcnt(0)" ::: "memory");
    __syncthreads();
    #pragma unroll
    for (int ko = 0; ko < 2; ko++){
      bf16x8 af[4], bfr[4];
      #pragma unroll
      for (int t = 0; t < 4; t++){
        af[t]  = *(const bf16x8*)(&As[(wm + t*16 + l16)*64 + ko*32 + quad*8]);
        bfr[t] = *(const bf16x8*)(&Bs[(wn + t*16 + l16)*64 + ko*32 + quad*8]);
      }
      #pragma unroll
      for (int mt = 0; mt < 4; mt++)
        #pragma unroll
        for (int nt = 0; nt < 4; nt++)
          acc[mt][nt] = __builtin_amdgcn_mfma_f32_16x16x32_bf16(
              af[mt], bfr[nt], acc[mt][nt], 0, 0, 0);
    }
    __syncthreads();
  }
  #pragma unroll
  for (int mt = 0; mt < 4; mt++){
    #pragma unroll
    for (int i = 0; i < 4; i++){
      int row = m0 + wm + mt*16 + quad*4 + i;
      if (row >= Mtot) continue;
      #pragma unroll
      for (int nt = 0; nt < 4; nt++){
        int col = n0 + wn + nt*16 + l16;
        size_t idx = (size_t)row * N + col;
        float vv = acc[mt][nt][i] + bias[col];
        if (EPI == 1){
          ((unsigned short*)Cout)[idx] = f2b(gelu_tanh(vv));
        } else if (EPI == 2){
          ((float*)Cout)[idx] = vv + res[idx];
        } else if (EPI == 5){
          int bb = row / M_;
          int mm = row - bb * M_;
          if (col < 384){
            ((unsigned short*)Cout)[(size_t)row * R_ + col] = f2b(vv);
          } else if (col < 768){
            ((unsigned short*)aux1)[(size_t)row * R_ + col - 384] = f2b(vv);
          } else {
            int c2 = col - 768;
            int hh = c2 >> 6, dd = c2 & 63;
            ((unsigned short*)aux2)[(((size_t)(bb*NH_ + hh))*DH_ + dd)*MPAD_ + mm] = f2b(vv);
          }
        } else {
          ((float*)Cout)[idx] = vv;
        }
      }
    }
  }
}

// ---------------- bf16 MFMA flash attention over M=1365 nodes ----------------
__global__ __launch_bounds__(256) void k_attn(
    const unsigned short* __restrict__ qb, const unsigned short* __restrict__ kb,
    const unsigned short* __restrict__ vtb, unsigned short* __restrict__ ob){
  __shared__ unsigned short Ks[64][64];
  __shared__ unsigned short Vt[64][64];
  __shared__ unsigned short Ps[4][16][64];
  int qt = blockIdx.x, bh = blockIdx.y;
  int b = bh / NH_, h = bh % NH_;
  int tid = threadIdx.x, wv = tid >> 6, lane = tid & 63;
  int quad = lane >> 4, l16 = lane & 15;

  int qm = qt*64 + wv*16 + l16;
  const unsigned short* qrow = qb + (size_t)(b*M_ + qm)*R_ + h*DH_;
  bf16x8 aq0 = *(const bf16x8*)(qrow + quad*8);
  bf16x8 aq1 = *(const bf16x8*)(qrow + 32 + quad*8);

  f32x4 oacc[4];
  #pragma unroll
  for (int db = 0; db < 4; db++) oacc[db] = 0.f;
  float mi[4], li[4];
  #pragma unroll
  for (int i = 0; i < 4; i++){ mi[i] = -1e30f; li[i] = 0.f; }

  for (int kt = 0; kt < 22; kt++){
    #pragma unroll
    for (int i = 0; i < 2; i++){
      int c = tid + i*256;
      int rowa = c >> 3, colc = (c & 7) * 8;
      *(uint4*)(&Ks[rowa][colc]) =
        *(const uint4*)(kb + (size_t)(b*M_ + kt*64 + rowa)*R_ + h*DH_ + colc);
      *(uint4*)(&Vt[rowa][colc]) =
        *(const uint4*)(vtb + ((size_t)bh*DH_ + rowa)*MPAD_ + kt*64 + colc);
    }
    __syncthreads();

    f32x4 s[4];
    #pragma unroll
    for (int nb = 0; nb < 4; nb++){
      s[nb] = 0.f;
      bf16x8 bk0 = *(const bf16x8*)(&Ks[nb*16 + l16][quad*8]);
      bf16x8 bk1 = *(const bf16x8*)(&Ks[nb*16 + l16][32 + quad*8]);
      s[nb] = __builtin_amdgcn_mfma_f32_16x16x32_bf16(aq0, bk0, s[nb], 0, 0, 0);
      s[nb] = __builtin_amdgcn_mfma_f32_16x16x32_bf16(aq1, bk1, s[nb], 0, 0, 0);
    }

    #pragma unroll
    for (int i = 0; i < 4; i++){
      float val[4];
      float mx = -1e30f;
      #pragma unroll
      for (int nb = 0; nb < 4; nb++){
        int gc = kt*64 + nb*16 + l16;
        val[nb] = (gc < M_) ? s[nb][i] * 0.125f : -1e30f;
        mx = fmaxf(mx, val[nb]);
      }
      mx = rmax16(mx);
      float mnew = fmaxf(mi[i], mx);
      float alpha = __expf(mi[i] - mnew);
      float rs = 0.f;
      #pragma unroll
      for (int nb = 0; nb < 4; nb++){
        float p = __expf(val[nb] - mnew);
        rs += p;
        Ps[wv][quad*4 + i][nb*16 + l16] = f2b(p);
      }
      rs = rsum16(rs);
      li[i] = li[i]*alpha + rs;
      mi[i] = mnew;
      #pragma unroll
      for (int db = 0; db < 4; db++) oacc[db][i] *= alpha;
    }

    #pragma unroll
    for (int ko = 0; ko < 2; ko++){
      bf16x8 ap = *(const bf16x8*)(&Ps[wv][l16][ko*32 + quad*8]);
      #pragma unroll
      for (int db = 0; db < 4; db++){
        bf16x8 bv = *(const bf16x8*)(&Vt[db*16 + l16][ko*32 + quad*8]);
        oacc[db] = __builtin_amdgcn_mfma_f32_16x16x32_bf16(ap, bv, oacc[db], 0, 0, 0);
      }
    }
    __syncthreads();
  }

  #pragma unroll
  for (int i = 0; i < 4; i++){
    int gm = qt*64 + wv*16 + quad*4 + i;
    if (gm < M_){
      float il = 1.f / li[i];
      #pragma unroll
      for (int db = 0; db < 4; db++)
        ob[(size_t)(b*M_ + gm)*R_ + h*DH_ + db*16 + l16] = f2b(oacc[db][i] * il);
    }
  }
}

// ---------------- scatter attn_out + residual -> d_out; LN2 -> flat bf16 ----------------
__global__ __launch_bounds__(256) void k_scatter_ln2(
    const float* __restrict__ x, const float* __restrict__ attn,
    const float* __restrict__ lw, const float* __restrict__ lb,
    float* __restrict__ xres, unsigned short* __restrict__ flatb){
  int row  = blockIdx.x * 4 + (threadIdx.x >> 6);
  int lane = threadIdx.x & 63;
  int l  = row % 6;
  int hw = (row / 6) & 1023;
  int b  = row / 6144;
  int h = hw >> 5, w = hw & 31;
  int off = (4096 - (4096 >> (2*l))) / 3;
  int id  = off + (h >> l) * (32 >> l) + (w >> l);
  const float* ar = attn + ((size_t)b * M_ + id) * R_;
  const float* xr = x + (size_t)row * R_;
  float* orow = xres + (size_t)row * R_;
  float vv[6]; float s = 0.f;
  #pragma unroll
  for (int i = 0; i < 6; i++){
    int r = lane + i*64;
    float t = xr[r] + ar[r];
    vv[i] = t; s += t; orow[r] = t;
  }
  s = wsum(s);
  float mu = s * (1.f/384.f);
  float qq = 0.f;
  #pragma unroll
  for (int i = 0; i < 6; i++){ float d = vv[i]-mu; qq += d*d; }
  qq = wsum(qq);
  float rs = rsqrtf(qq * (1.f/384.f) + 1e-5f);
  unsigned short* fr = flatb + (size_t)row * R_;
  #pragma unroll
  for (int i = 0; i < 6; i++){
    int r = lane + i*64;
    fr[r] = f2b((vv[i]-mu)*rs*lw[r] + lb[r]);
  }
}

extern "C" void kernel_launch(void* const* d_in, const int* in_sizes, int n_in,
                              void* d_out, int out_size, void* d_ws, size_t ws_size,
                              hipStream_t stream){
  const float* x    = (const float*)d_in[0];
  const float* ln1w = (const float*)d_in[1];
  const float* ln1b = (const float*)d_in[2];
  const float* ln2w = (const float*)d_in[3];
  const float* ln2b = (const float*)d_in[4];
  const float* wq   = (const float*)d_in[5];
  const float* bq   = (const float*)d_in[6];
  const float* wk   = (const float*)d_in[7];
  const float* bk   = (const float*)d_in[8];
  const float* wvv  = (const float*)d_in[9];
  const float* bv   = (const float*)d_in[10];
  const float* wo   = (const float*)d_in[11];
  const float* bo   = (const float*)d_in[12];
  const float* w1   = (const float*)d_in[13];
  const float* b1   = (const float*)d_in[14];
  const float* w2   = (const float*)d_in[15];
  const float* b2   = (const float*)d_in[16];
  float* out = (float*)d_out;

  // ---- workspace layout ----
  char* ws = (char*)d_ws;
  unsigned short* h1b = (unsigned short*)ws;                     // 8192*9216 bf16 (reuses region A)
  unsigned short* qb  = (unsigned short*)ws;
  unsigned short* kb  = qb + (size_t)BMR_ * R_;
  unsigned short* vtb = kb + (size_t)BMR_ * R_;
  unsigned short* ob  = vtb + (size_t)B_ * NH_ * DH_ * MPAD_;
  float* attn_o = (float*)(ob + (size_t)BMR_ * R_);
  size_t regA = ((size_t)8192 * HID_ * 2 + 255) & ~(size_t)255;
  char* p = ws + regA;
  float* uniqf = (float*)p;                   p += (size_t)BMR_ * R_ * 4;
  unsigned short* uniqb = (unsigned short*)p; p += (size_t)BMR_ * R_ * 2;
  unsigned short* wqkvt = (unsigned short*)p; p += (size_t)3 * R_ * R_ * 2;
  unsigned short* wot = (unsigned short*)p;   p += (size_t)R_ * R_ * 2;
  unsigned short* w1t = (unsigned short*)p;   p += (size_t)NE_ * HID_ * 2;
  unsigned short* w2t = (unsigned short*)p;   p += (size_t)NE_ * HID_ * 2;
  unsigned short* flatb = (unsigned short*)p; p += (size_t)NROW_ * R_ * 2;
  float* bqkv = (float*)p;                    p += (size_t)3 * R_ * 4;

  hipMemsetAsync(uniqf, 0, (size_t)BMR_ * R_ * 4, stream);
  hipMemsetAsync(vtb, 0, (size_t)B_ * NH_ * DH_ * MPAD_ * 2, stream);
  hipMemcpyAsync(bqkv,        bq, R_*4, hipMemcpyDeviceToDevice, stream);
  hipMemcpyAsync(bqkv + R_,   bk, R_*4, hipMemcpyDeviceToDevice, stream);
  hipMemcpyAsync(bqkv + 2*R_, bv, R_*4, hipMemcpyDeviceToDevice, stream);

  k_ln1_scatter<<<NROW_/4, 256, 0, stream>>>(x, ln1w, ln1b, uniqf);
  k_cvt<<<(BMR_*R_ + 255)/256, 256, 0, stream>>>(uniqf, uniqb, BMR_*R_);

  dim3 tb(32, 8);
  k_tcvt<<<dim3(R_/32, R_/32), tb, 0, stream>>>(wq, wqkvt, R_, R_);
  k_tcvt<<<dim3(R_/32, R_/32), tb, 0, stream>>>(wk, wqkvt + (size_t)R_*R_, R_, R_);
  k_tcvt<<<dim3(R_/32, R_/32), tb, 0, stream>>>(wvv, wqkvt + (size_t)2*R_*R_, R_, R_);
  k_tcvt<<<dim3(R_/32, R_/32), tb, 0, stream>>>(wo, wot, R_, R_);
  k_tcvt<<<dim3(HID_/32, NE_/32), tb, 0, stream>>>(w1, w1t, NE_, HID_);
  k_tcvt<<<dim3(NE_/32, HID_/32), tb, 0, stream>>>(w2, w2t, HID_, NE_);

  // merged QKV: N = 1152
  k_gemm<5><<<dim3(86, 9), 256, 0, stream>>>(uniqb, wqkvt, bqkv, qb, nullptr,
                                             kb, vtb, BMR_, 3*R_, R_);

  k_attn<<<dim3(22, 48), 256, 0, stream>>>(qb, kb, vtb, ob);

  k_gemm<0><<<dim3(86, 3), 256, 0, stream>>>(ob, wot, bo, attn_o, nullptr,
                                             nullptr, nullptr, BMR_, R_, R_);

  k_scatter_ln2<<<NROW_/4, 256, 0, stream>>>(x, attn_o, ln2w, ln2b, out, flatb);

  k_gemm<1><<<dim3(64, 72), 256, 0, stream>>>(flatb, w1t, b1, h1b, nullptr,
                                              nullptr, nullptr, 8192, HID_, NE_);
  k_gemm<2><<<dim3(64, 18), 256, 0, stream>>>(h1b, w2t, b2, out, out,
                                              nullptr, nullptr, 8192, NE_, HID_);
}